// Round 7
// baseline (251.432 us; speedup 1.0000x reference)
//
#include <hip/hip_runtime.h>

#define NPTS 262144
#define HALF_PTS 131072
#define HP1 2654435761u
#define HP2 805459861u
#define TMASK 0x7FFFFu

typedef __attribute__((ext_vector_type(8))) short short8;
typedef __attribute__((ext_vector_type(4))) float f32x4;
typedef __attribute__((ext_vector_type(2))) float f32x2;
typedef unsigned short ushort_t;
typedef unsigned int uint_t;

#define MFMA(a, b, c) __builtin_amdgcn_mfma_f32_16x16x32_bf16((a), (b), (c), 0, 0, 0)

__device__ __forceinline__ ushort_t f2bf(float f) {
    uint_t u = __float_as_uint(f);
    return (ushort_t)((u + 0x7FFFu + ((u >> 16) & 1u)) >> 16);
}
__device__ __forceinline__ float sigmoidf_fast(float v) {
    return 1.0f / (1.0f + __expf(-v));
}

// ws layout: [0,16MB) feats (packed bf16 pair per point-level), [16MB,+24KB) weight frags
#define WS_WF_OFF (16u * 1024u * 1024u)

// Weight-fragment offsets (ushort elements)
#define OFF_DW1 0
#define OFF_DW2 2048
#define OFF_CW1 3072
#define OFF_CW2 7168
#define OFF_CW3 11264
#define WF_TOTAL 12288

// ---------------- Kernel 0: pack weights into bf16 MFMA B-fragments ----------------
extern "C" __global__ void ngp_prep(
    const float* __restrict__ dW1, const float* __restrict__ dW2,
    const float* __restrict__ cW1, const float* __restrict__ cW2,
    const float* __restrict__ cW3, ushort_t* __restrict__ wf)
{
    const int e = blockIdx.x * 256 + (int)threadIdx.x;
    if (e >= WF_TOTAL) return;
    const float* W; int base, NT, KR, NR;
    if (e < OFF_DW2)      { W = dW1; base = OFF_DW1; NT = 4; KR = 32; NR = 64; }
    else if (e < OFF_CW1) { W = dW2; base = OFF_DW2; NT = 1; KR = 64; NR = 16; }
    else if (e < OFF_CW2) { W = cW1; base = OFF_CW1; NT = 4; KR = 43; NR = 64; }
    else if (e < OFF_CW3) { W = cW2; base = OFF_CW2; NT = 4; KR = 64; NR = 64; }
    else                  { W = cW3; base = OFF_CW3; NT = 1; KR = 64; NR = 3;  }
    const int r = e - base;
    const int frag = r >> 9;
    const int lane = (r >> 3) & 63;
    const int j = r & 7;
    const int kc = frag / NT, nt = frag % NT;
    const int k = kc * 32 + ((lane >> 4) << 3) + j;
    const int n = nt * 16 + (lane & 15);
    const float v = (k < KR && n < NR) ? W[k * NR + n] : 0.0f;
    wf[e] = f2bf(v);
}

// ---------------- Kernel A: hash-grid encode, 2 points/thread, nt gathers ----------------
// grid = 16 levels x 512 blocks; level uniform per block. Each thread handles
// points pt and pt+131072 at one level: 16 independent corner gathers issued
// before any interpolation (2x memory-level parallelism vs R3).
extern "C" __global__ void __launch_bounds__(256) ngp_encode(
    const float* __restrict__ xin, const float* __restrict__ tbl,
    uint_t* __restrict__ feats)
{
    const int b  = blockIdx.x;
    const int l  = b >> 9;
    const int pt = ((b & 511) << 8) + (int)threadIdx.x;   // [0, 131072)

    static const float NLs[16] = {16.f, 22.f, 30.f, 42.f, 58.f, 80.f, 111.f, 153.f,
                                  212.f, 294.f, 406.f, 561.f, 776.f, 1072.f, 1482.f, 2048.f};
    const float nl = NLs[l];
    const f32x2* tp = (const f32x2*)tbl + ((size_t)l << 19);

    // ---- point A ----
    const float xA0 = xin[3 * pt + 0];
    const float xA1 = xin[3 * pt + 1];
    const float xA2 = xin[3 * pt + 2];
    const bool mA = (fabsf(xA0) < 1.5f) & (fabsf(xA1) < 1.5f) & (fabsf(xA2) < 1.5f);
    // ---- point B ----
    const int ptB = pt + HALF_PTS;
    const float xB0 = xin[3 * ptB + 0];
    const float xB1 = xin[3 * ptB + 1];
    const float xB2 = xin[3 * ptB + 2];
    const bool mB = (fabsf(xB0) < 1.5f) & (fabsf(xB1) < 1.5f) & (fabsf(xB2) < 1.5f);

    unsigned iA[8], iB[8];
    float lA0 = 0.f, lA1 = 0.f, lA2 = 0.f, lB0 = 0.f, lB1 = 0.f, lB2 = 0.f;
    f32x2 cA[8], cB[8];

    if (mA) {
        const float s0 = (xA0 / 3.0f + 0.5f) * nl;
        const float s1 = (xA1 / 3.0f + 0.5f) * nl;
        const float s2 = (xA2 / 3.0f + 0.5f) * nl;
        const float f0 = floorf(s0), f1 = floorf(s1), f2 = floorf(s2);
        lA0 = s0 - f0; lA1 = s1 - f1; lA2 = s2 - f2;
        const unsigned va0 = (unsigned)(int)f0, vb0 = va0 + 1u;
        const unsigned va1 = (unsigned)(int)f1 * HP1, vb1 = va1 + HP1;
        const unsigned va2 = (unsigned)(int)f2 * HP2, vb2 = va2 + HP2;
        iA[0] = (va0 ^ va1 ^ va2) & TMASK;
        iA[1] = (vb0 ^ va1 ^ va2) & TMASK;
        iA[2] = (va0 ^ vb1 ^ va2) & TMASK;
        iA[3] = (vb0 ^ vb1 ^ va2) & TMASK;
        iA[4] = (va0 ^ va1 ^ vb2) & TMASK;
        iA[5] = (vb0 ^ va1 ^ vb2) & TMASK;
        iA[6] = (va0 ^ vb1 ^ vb2) & TMASK;
        iA[7] = (vb0 ^ vb1 ^ vb2) & TMASK;
    }
    if (mB) {
        const float s0 = (xB0 / 3.0f + 0.5f) * nl;
        const float s1 = (xB1 / 3.0f + 0.5f) * nl;
        const float s2 = (xB2 / 3.0f + 0.5f) * nl;
        const float f0 = floorf(s0), f1 = floorf(s1), f2 = floorf(s2);
        lB0 = s0 - f0; lB1 = s1 - f1; lB2 = s2 - f2;
        const unsigned va0 = (unsigned)(int)f0, vb0 = va0 + 1u;
        const unsigned va1 = (unsigned)(int)f1 * HP1, vb1 = va1 + HP1;
        const unsigned va2 = (unsigned)(int)f2 * HP2, vb2 = va2 + HP2;
        iB[0] = (va0 ^ va1 ^ va2) & TMASK;
        iB[1] = (vb0 ^ va1 ^ va2) & TMASK;
        iB[2] = (va0 ^ vb1 ^ va2) & TMASK;
        iB[3] = (vb0 ^ vb1 ^ va2) & TMASK;
        iB[4] = (va0 ^ va1 ^ vb2) & TMASK;
        iB[5] = (vb0 ^ va1 ^ vb2) & TMASK;
        iB[6] = (va0 ^ vb1 ^ vb2) & TMASK;
        iB[7] = (vb0 ^ vb1 ^ vb2) & TMASK;
    }
    // Issue all 16 gathers before any interpolation (max loads in flight).
    if (mA) {
        #pragma unroll
        for (int k = 0; k < 8; ++k) cA[k] = __builtin_nontemporal_load(tp + iA[k]);
    }
    if (mB) {
        #pragma unroll
        for (int k = 0; k < 8; ++k) cB[k] = __builtin_nontemporal_load(tp + iB[k]);
    }
    if (mA) {
        const float m0 = 1.0f - lA0, m1 = 1.0f - lA1, m2 = 1.0f - lA2;
        float a = 0.0f, bb = 0.0f, w;
        w = m0 * m1 * m2;  a = fmaf(w, cA[0].x, a); bb = fmaf(w, cA[0].y, bb);
        w = lA0 * m1 * m2; a = fmaf(w, cA[1].x, a); bb = fmaf(w, cA[1].y, bb);
        w = m0 * lA1 * m2; a = fmaf(w, cA[2].x, a); bb = fmaf(w, cA[2].y, bb);
        w = lA0 * lA1 * m2; a = fmaf(w, cA[3].x, a); bb = fmaf(w, cA[3].y, bb);
        w = m0 * m1 * lA2;  a = fmaf(w, cA[4].x, a); bb = fmaf(w, cA[4].y, bb);
        w = lA0 * m1 * lA2; a = fmaf(w, cA[5].x, a); bb = fmaf(w, cA[5].y, bb);
        w = m0 * lA1 * lA2; a = fmaf(w, cA[6].x, a); bb = fmaf(w, cA[6].y, bb);
        w = lA0 * lA1 * lA2; a = fmaf(w, cA[7].x, a); bb = fmaf(w, cA[7].y, bb);
        feats[(size_t)l * NPTS + pt] = (uint_t)f2bf(a) | ((uint_t)f2bf(bb) << 16);
    }
    if (mB) {
        const float m0 = 1.0f - lB0, m1 = 1.0f - lB1, m2 = 1.0f - lB2;
        float a = 0.0f, bb = 0.0f, w;
        w = m0 * m1 * m2;  a = fmaf(w, cB[0].x, a); bb = fmaf(w, cB[0].y, bb);
        w = lB0 * m1 * m2; a = fmaf(w, cB[1].x, a); bb = fmaf(w, cB[1].y, bb);
        w = m0 * lB1 * m2; a = fmaf(w, cB[2].x, a); bb = fmaf(w, cB[2].y, bb);
        w = lB0 * lB1 * m2; a = fmaf(w, cB[3].x, a); bb = fmaf(w, cB[3].y, bb);
        w = m0 * m1 * lB2;  a = fmaf(w, cB[4].x, a); bb = fmaf(w, cB[4].y, bb);
        w = lB0 * m1 * lB2; a = fmaf(w, cB[5].x, a); bb = fmaf(w, cB[5].y, bb);
        w = m0 * lB1 * lB2; a = fmaf(w, cB[6].x, a); bb = fmaf(w, cB[6].y, bb);
        w = lB0 * lB1 * lB2; a = fmaf(w, cB[7].x, a); bb = fmaf(w, cB[7].y, bb);
        feats[(size_t)l * NPTS + ptB] = (uint_t)f2bf(a) | ((uint_t)f2bf(bb) << 16);
    }
}

// ---------------- Kernel B: MFMA MLPs (R3-verified) ----------------
extern "C" __global__ void __launch_bounds__(256) ngp_mlp(
    const float* __restrict__ xin, const float* __restrict__ din,
    const uint_t* __restrict__ featsbf, const ushort_t* __restrict__ wf,
    const float* __restrict__ db1, const float* __restrict__ db2,
    const float* __restrict__ cb1, const float* __restrict__ cb2,
    const float* __restrict__ cb3,
    float* __restrict__ out)
{
    __shared__ short act[4][4096];
    __shared__ float mk[4][64];

    const int w    = (int)threadIdx.x >> 6;
    const int lane = (int)threadIdx.x & 63;
    const int lrow = lane & 15;
    const int lq   = lane >> 4;
    const int ptb  = blockIdx.x * 256 + w * 64;
    const int p    = ptb + lane;
    char* Ab = (char*)&act[w][0];

#define LDSA(mt, kc) (*reinterpret_cast<const short8*>(Ab + ((((mt) * 16 + lrow) * 128 + (kc) * 64 + lq * 16) ^ ((lrow & 7) << 4))))
#define LOADB(off)   (*reinterpret_cast<const short8*>(wf + (off) + lane * 8))
#define STB16(row, col, val) *reinterpret_cast<ushort_t*>(Ab + ((((row) * 128 + (col) * 2)) ^ (((row) & 7) << 4))) = (val)

    const float x0 = xin[3 * p + 0];
    const float x1 = xin[3 * p + 1];
    const float x2 = xin[3 * p + 2];
    const bool msk = (fabsf(x0) < 1.5f) & (fabsf(x1) < 1.5f) & (fabsf(x2) < 1.5f);
    mk[w][lane] = msk ? 1.0f : 0.0f;

    uint_t u[16];
    #pragma unroll
    for (int l = 0; l < 16; ++l) u[l] = featsbf[(size_t)l * NPTS + p];
    #pragma unroll
    for (int c = 0; c < 4; ++c) {
        short8 v;
        #pragma unroll
        for (int q = 0; q < 4; ++q) {
            v[2 * q + 0] = (short)(u[4 * c + q] & 0xFFFFu);
            v[2 * q + 1] = (short)(u[4 * c + q] >> 16);
        }
        const int byte = (lane * 128 + 16 * c) ^ ((lane & 7) << 4);
        *reinterpret_cast<short8*>(Ab + byte) = v;
    }
    const float d0v = din[3 * p + 0];
    const float d1v = din[3 * p + 1];
    const float d2v = din[3 * p + 2];

    __syncthreads();

    // ---- Layer D1: feats[64x32] @ dW1[32x64] ----
    f32x4 acc[4][4];
    #pragma unroll
    for (int nt = 0; nt < 4; ++nt) {
        const float b = db1[nt * 16 + lrow];
        #pragma unroll
        for (int mt = 0; mt < 4; ++mt) acc[mt][nt] = (f32x4){b, b, b, b};
    }
    {
        short8 a0 = LDSA(0, 0), a1 = LDSA(1, 0), a2 = LDSA(2, 0), a3 = LDSA(3, 0);
        #pragma unroll
        for (int nt = 0; nt < 4; ++nt) {
            const short8 B = LOADB(OFF_DW1 + nt * 512);
            acc[0][nt] = MFMA(a0, B, acc[0][nt]);
            acc[1][nt] = MFMA(a1, B, acc[1][nt]);
            acc[2][nt] = MFMA(a2, B, acc[2][nt]);
            acc[3][nt] = MFMA(a3, B, acc[3][nt]);
        }
    }
    __syncthreads();
    #pragma unroll
    for (int mt = 0; mt < 4; ++mt)
        #pragma unroll
        for (int nt = 0; nt < 4; ++nt)
            #pragma unroll
            for (int r = 0; r < 4; ++r) {
                const int row = mt * 16 + lq * 4 + r;
                STB16(row, nt * 16 + lrow, f2bf(fmaxf(acc[mt][nt][r], 0.0f)));
            }
    __syncthreads();

    // ---- Layer D2: hid[64x64] @ dW2[64x16] ----
    f32x4 hD[4];
    {
        const float b = db2[lrow];
        #pragma unroll
        for (int mt = 0; mt < 4; ++mt) hD[mt] = (f32x4){b, b, b, b};
        #pragma unroll
        for (int kc = 0; kc < 2; ++kc) {
            const short8 B = LOADB(OFF_DW2 + kc * 512);
            #pragma unroll
            for (int mt = 0; mt < 4; ++mt) hD[mt] = MFMA(LDSA(mt, kc), B, hD[mt]);
        }
    }
    __syncthreads();

    if (lrow == 0) {
        #pragma unroll
        for (int mt = 0; mt < 4; ++mt)
            #pragma unroll
            for (int r = 0; r < 4; ++r) {
                const int row = mt * 16 + lq * 4 + r;
                const float mm = mk[w][row];
                out[3 * NPTS + ptb + row] = (mm != 0.0f) ? __expf(hD[mt][r]) : 0.0f;
            }
    }
    #pragma unroll
    for (int mt = 0; mt < 4; ++mt)
        #pragma unroll
        for (int r = 0; r < 4; ++r) {
            const int row = mt * 16 + lq * 4 + r;
            STB16(row, lrow, f2bf(hD[mt][r]));
        }
    {
        ushort_t t[48];
        t[0] = f2bf(d0v); t[1] = f2bf(d1v); t[2] = f2bf(d2v);
        #pragma unroll
        for (int j = 0; j < 4; ++j) {
            const float s = (float)(1 << j);
            t[3 + 6 * j + 0] = f2bf(__sinf(s * d0v));
            t[3 + 6 * j + 1] = f2bf(__sinf(s * d1v));
            t[3 + 6 * j + 2] = f2bf(__sinf(s * d2v));
            t[3 + 6 * j + 3] = f2bf(__cosf(s * d0v));
            t[3 + 6 * j + 4] = f2bf(__cosf(s * d1v));
            t[3 + 6 * j + 5] = f2bf(__cosf(s * d2v));
        }
        #pragma unroll
        for (int i = 27; i < 48; ++i) t[i] = 0;
        #pragma unroll
        for (int c = 0; c < 6; ++c) {
            short8 v;
            #pragma unroll
            for (int j = 0; j < 8; ++j) v[j] = (short)t[8 * c + j];
            const int byte = (lane * 128 + 32 + 16 * c) ^ ((lane & 7) << 4);
            *reinterpret_cast<short8*>(Ab + byte) = v;
        }
    }
    __syncthreads();

    // ---- Layer C1: ch[64x64(43)] @ cW1[64x64] ----
    #pragma unroll
    for (int nt = 0; nt < 4; ++nt) {
        const float b = cb1[nt * 16 + lrow];
        #pragma unroll
        for (int mt = 0; mt < 4; ++mt) acc[mt][nt] = (f32x4){b, b, b, b};
    }
    #pragma unroll
    for (int kc = 0; kc < 2; ++kc) {
        short8 a0 = LDSA(0, kc), a1 = LDSA(1, kc), a2 = LDSA(2, kc), a3 = LDSA(3, kc);
        #pragma unroll
        for (int nt = 0; nt < 4; ++nt) {
            const short8 B = LOADB(OFF_CW1 + (kc * 4 + nt) * 512);
            acc[0][nt] = MFMA(a0, B, acc[0][nt]);
            acc[1][nt] = MFMA(a1, B, acc[1][nt]);
            acc[2][nt] = MFMA(a2, B, acc[2][nt]);
            acc[3][nt] = MFMA(a3, B, acc[3][nt]);
        }
    }
    __syncthreads();
    #pragma unroll
    for (int mt = 0; mt < 4; ++mt)
        #pragma unroll
        for (int nt = 0; nt < 4; ++nt)
            #pragma unroll
            for (int r = 0; r < 4; ++r) {
                const int row = mt * 16 + lq * 4 + r;
                STB16(row, nt * 16 + lrow, f2bf(fmaxf(acc[mt][nt][r], 0.0f)));
            }
    __syncthreads();

    // ---- Layer C2: c1[64x64] @ cW2[64x64] ----
    #pragma unroll
    for (int nt = 0; nt < 4; ++nt) {
        const float b = cb2[nt * 16 + lrow];
        #pragma unroll
        for (int mt = 0; mt < 4; ++mt) acc[mt][nt] = (f32x4){b, b, b, b};
    }
    #pragma unroll
    for (int kc = 0; kc < 2; ++kc) {
        short8 a0 = LDSA(0, kc), a1 = LDSA(1, kc), a2 = LDSA(2, kc), a3 = LDSA(3, kc);
        #pragma unroll
        for (int nt = 0; nt < 4; ++nt) {
            const short8 B = LOADB(OFF_CW2 + (kc * 4 + nt) * 512);
            acc[0][nt] = MFMA(a0, B, acc[0][nt]);
            acc[1][nt] = MFMA(a1, B, acc[1][nt]);
            acc[2][nt] = MFMA(a2, B, acc[2][nt]);
            acc[3][nt] = MFMA(a3, B, acc[3][nt]);
        }
    }
    __syncthreads();
    #pragma unroll
    for (int mt = 0; mt < 4; ++mt)
        #pragma unroll
        for (int nt = 0; nt < 4; ++nt)
            #pragma unroll
            for (int r = 0; r < 4; ++r) {
                const int row = mt * 16 + lq * 4 + r;
                STB16(row, nt * 16 + lrow, f2bf(fmaxf(acc[mt][nt][r], 0.0f)));
            }
    __syncthreads();

    // ---- Layer C3: c2[64x64] @ cW3[64x3(pad16)] ----
    f32x4 rD[4];
    {
        const float b = (lrow < 3) ? cb3[lrow] : 0.0f;
        #pragma unroll
        for (int mt = 0; mt < 4; ++mt) rD[mt] = (f32x4){b, b, b, b};
        #pragma unroll
        for (int kc = 0; kc < 2; ++kc) {
            const short8 B = LOADB(OFF_CW3 + kc * 512);
            #pragma unroll
            for (int mt = 0; mt < 4; ++mt) rD[mt] = MFMA(LDSA(mt, kc), B, rD[mt]);
        }
    }
    if (lrow < 3) {
        #pragma unroll
        for (int mt = 0; mt < 4; ++mt)
            #pragma unroll
            for (int r = 0; r < 4; ++r) {
                const int row = mt * 16 + lq * 4 + r;
                const float mm = mk[w][row];
                out[3 * (ptb + row) + lrow] = (mm != 0.0f) ? sigmoidf_fast(rD[mt][r]) : 0.0f;
            }
    }
#undef LDSA
#undef LOADB
#undef STB16
}

extern "C" void kernel_launch(void* const* d_in, const int* in_sizes, int n_in,
                              void* d_out, int out_size, void* d_ws, size_t ws_size,
                              hipStream_t stream) {
    const float* x    = (const float*)d_in[0];
    const float* d    = (const float*)d_in[1];
    const float* tbl  = (const float*)d_in[2];
    const float* dW1  = (const float*)d_in[3];
    const float* db1  = (const float*)d_in[4];
    const float* dW2  = (const float*)d_in[5];
    const float* db2  = (const float*)d_in[6];
    const float* cW1  = (const float*)d_in[7];
    const float* cb1  = (const float*)d_in[8];
    const float* cW2  = (const float*)d_in[9];
    const float* cb2  = (const float*)d_in[10];
    const float* cW3  = (const float*)d_in[11];
    const float* cb3  = (const float*)d_in[12];

    uint_t* feats = (uint_t*)d_ws;                               // 16 MB
    ushort_t* wfr = (ushort_t*)((char*)d_ws + WS_WF_OFF);        // 24 KB

    ngp_prep<<<48, 256, 0, stream>>>(dW1, dW2, cW1, cW2, cW3, wfr);
    ngp_encode<<<16 * 512, 256, 0, stream>>>(x, tbl, feats);
    ngp_mlp<<<NPTS / 256, 256, 0, stream>>>(
        x, d, feats, wfr, db1, db2, cb1, cb2, cb3, (float*)d_out);
}

// Round 8
// 111.248 us; speedup vs baseline: 2.2601x; 2.2601x over previous
//
#include <hip/hip_runtime.h>

#define NPTS 262144
#define HALF_PTS 131072
#define HP1 2654435761u
#define HP2 805459861u
#define TMASK 0x7FFFFu

typedef __attribute__((ext_vector_type(8))) short short8;
typedef __attribute__((ext_vector_type(4))) float f32x4;
typedef unsigned short ushort_t;
typedef unsigned int uint_t;

#define MFMA(a, b, c) __builtin_amdgcn_mfma_f32_16x16x32_bf16((a), (b), (c), 0, 0, 0)

__device__ __forceinline__ ushort_t f2bf(float f) {
    uint_t u = __float_as_uint(f);
    return (ushort_t)((u + 0x7FFFu + ((u >> 16) & 1u)) >> 16);
}
__device__ __forceinline__ float sigmoidf_fast(float v) {
    return 1.0f / (1.0f + __expf(-v));
}

// Dense re-layout for levels 0..4 (dims 17,23,31,43,59), 16B/entry (both x-corners).
#define D0 4913
#define D1 12167
#define D2 29791
#define D3 79507
#define D4 205379
#define DOFF0 0
#define DOFF1 4913
#define DOFF2 17080
#define DOFF3 46871
#define DOFF4 126378
#define DTOT  331757

// ws layout (bytes): [0,16MB) feats, [16MB, +5.31MB) dense, [22MB,+24KB) weight frags
#define WS_DN_OFF (16u * 1024u * 1024u)
#define WS_WF_OFF (22u * 1024u * 1024u)

// Weight-fragment offsets (ushort elements)
#define OFF_DW1 0
#define OFF_DW2 2048
#define OFF_CW1 3072
#define OFF_CW2 7168
#define OFF_CW3 11264
#define WF_TOTAL 12288

// ---------------- Kernel 0a: pack weights into bf16 MFMA B-fragments ----------------
extern "C" __global__ void ngp_prep(
    const float* __restrict__ dW1, const float* __restrict__ dW2,
    const float* __restrict__ cW1, const float* __restrict__ cW2,
    const float* __restrict__ cW3, ushort_t* __restrict__ wf)
{
    const int e = blockIdx.x * 256 + (int)threadIdx.x;
    if (e >= WF_TOTAL) return;
    const float* W; int base, NT, KR, NR;
    if (e < OFF_DW2)      { W = dW1; base = OFF_DW1; NT = 4; KR = 32; NR = 64; }
    else if (e < OFF_CW1) { W = dW2; base = OFF_DW2; NT = 1; KR = 64; NR = 16; }
    else if (e < OFF_CW2) { W = cW1; base = OFF_CW1; NT = 4; KR = 43; NR = 64; }
    else if (e < OFF_CW3) { W = cW2; base = OFF_CW2; NT = 4; KR = 64; NR = 64; }
    else                  { W = cW3; base = OFF_CW3; NT = 1; KR = 64; NR = 3;  }
    const int r = e - base;
    const int frag = r >> 9;
    const int lane = (r >> 3) & 63;
    const int j = r & 7;
    const int kc = frag / NT, nt = frag % NT;
    const int k = kc * 32 + ((lane >> 4) << 3) + j;
    const int n = nt * 16 + (lane & 15);
    const float v = (k < KR && n < NR) ? W[k * NR + n] : 0.0f;
    wf[e] = f2bf(v);
}

// ---------------- Kernel 0b: densify levels 0..4 ----------------
// dense[e] = { tbl[l][hash(v)], tbl[l][hash(v+ex)] } at (l, v0,v1,v2).
extern "C" __global__ void ngp_dense(
    const float* __restrict__ tbl, f32x4* __restrict__ dense)
{
    const int e = blockIdx.x * 256 + (int)threadIdx.x;
    if (e >= DTOT) return;
    int l, base, dim;
    if (e < DOFF1)      { l = 0; base = DOFF0; dim = 17; }
    else if (e < DOFF2) { l = 1; base = DOFF1; dim = 23; }
    else if (e < DOFF3) { l = 2; base = DOFF2; dim = 31; }
    else if (e < DOFF4) { l = 3; base = DOFF3; dim = 43; }
    else                { l = 4; base = DOFF4; dim = 59; }
    const int r = e - base;
    const int v0 = r % dim;
    const int t  = r / dim;
    const int v1 = t % dim;
    const int v2 = t / dim;
    const float2* tp = (const float2*)tbl + ((size_t)l << 19);
    const unsigned hy = (unsigned)v1 * HP1;
    const unsigned hz = (unsigned)v2 * HP2;
    const unsigned h0 = ((unsigned)v0 ^ hy ^ hz) & TMASK;
    const unsigned h1 = (((unsigned)v0 + 1u) ^ hy ^ hz) & TMASK;
    const float2 c0 = tp[h0];
    const float2 c1 = tp[h1];
    dense[e] = (f32x4){c0.x, c0.y, c1.x, c1.y};
}

// ---------------- Kernel A: hash-grid encode ----------------
// grid = 16 levels x 512 blocks; level uniform per block; 2 points/thread.
// Levels 0..4: dense array, 4 aligned 16B loads/point (x-pair packed).
// Levels 5..15: hash table, 8 cached 8B gathers/point, all issued up-front.
extern "C" __global__ void __launch_bounds__(256) ngp_encode(
    const float* __restrict__ xin, const float* __restrict__ tbl,
    const f32x4* __restrict__ dense, uint_t* __restrict__ feats)
{
    const int b  = blockIdx.x;
    const int l  = b >> 9;
    const int pt = ((b & 511) << 8) + (int)threadIdx.x;   // [0, 131072)

    static const float NLs[16] = {16.f, 22.f, 30.f, 42.f, 58.f, 80.f, 111.f, 153.f,
                                  212.f, 294.f, 406.f, 561.f, 776.f, 1072.f, 1482.f, 2048.f};
    static const int DDIM[5] = {17, 23, 31, 43, 59};
    static const int DOFF[5] = {DOFF0, DOFF1, DOFF2, DOFF3, DOFF4};
    const float nl = NLs[l];

    // ---- point A ----
    const float xA0 = xin[3 * pt + 0];
    const float xA1 = xin[3 * pt + 1];
    const float xA2 = xin[3 * pt + 2];
    const bool mA = (fabsf(xA0) < 1.5f) & (fabsf(xA1) < 1.5f) & (fabsf(xA2) < 1.5f);
    // ---- point B ----
    const int ptB = pt + HALF_PTS;
    const float xB0 = xin[3 * ptB + 0];
    const float xB1 = xin[3 * ptB + 1];
    const float xB2 = xin[3 * ptB + 2];
    const bool mB = (fabsf(xB0) < 1.5f) & (fabsf(xB1) < 1.5f) & (fabsf(xB2) < 1.5f);

    float sA0 = 0.f, sA1 = 0.f, sA2 = 0.f, sB0 = 0.f, sB1 = 0.f, sB2 = 0.f;
    if (mA) {
        sA0 = (xA0 / 3.0f + 0.5f) * nl;
        sA1 = (xA1 / 3.0f + 0.5f) * nl;
        sA2 = (xA2 / 3.0f + 0.5f) * nl;
    }
    if (mB) {
        sB0 = (xB0 / 3.0f + 0.5f) * nl;
        sB1 = (xB1 / 3.0f + 0.5f) * nl;
        sB2 = (xB2 / 3.0f + 0.5f) * nl;
    }
    const float fA0 = floorf(sA0), fA1 = floorf(sA1), fA2 = floorf(sA2);
    const float fB0 = floorf(sB0), fB1 = floorf(sB1), fB2 = floorf(sB2);
    const float lA0 = sA0 - fA0, lA1 = sA1 - fA1, lA2 = sA2 - fA2;
    const float lB0 = sB0 - fB0, lB1 = sB1 - fB1, lB2 = sB2 - fB2;

    if (l < 5) {
        // ---------- dense path ----------
        const int dim = DDIM[l];
        const f32x4* dp = dense + DOFF[l];
        f32x4 A00, A10, A01, A11, B00, B10, B01, B11;
        if (mA) {
            const int idx = ((int)fA2 * dim + (int)fA1) * dim + (int)fA0;
            A00 = dp[idx];
            A10 = dp[idx + dim];
            A01 = dp[idx + dim * dim];
            A11 = dp[idx + dim * dim + dim];
        }
        if (mB) {
            const int idx = ((int)fB2 * dim + (int)fB1) * dim + (int)fB0;
            B00 = dp[idx];
            B10 = dp[idx + dim];
            B01 = dp[idx + dim * dim];
            B11 = dp[idx + dim * dim + dim];
        }
        if (mA) {
            const float m0 = 1.0f - lA0, m1 = 1.0f - lA1, m2 = 1.0f - lA2;
            float a = 0.0f, bb = 0.0f, w;
            w = m0 * m1 * m2;   a = fmaf(w, A00[0], a); bb = fmaf(w, A00[1], bb);
            w = lA0 * m1 * m2;  a = fmaf(w, A00[2], a); bb = fmaf(w, A00[3], bb);
            w = m0 * lA1 * m2;  a = fmaf(w, A10[0], a); bb = fmaf(w, A10[1], bb);
            w = lA0 * lA1 * m2; a = fmaf(w, A10[2], a); bb = fmaf(w, A10[3], bb);
            w = m0 * m1 * lA2;  a = fmaf(w, A01[0], a); bb = fmaf(w, A01[1], bb);
            w = lA0 * m1 * lA2; a = fmaf(w, A01[2], a); bb = fmaf(w, A01[3], bb);
            w = m0 * lA1 * lA2; a = fmaf(w, A11[0], a); bb = fmaf(w, A11[1], bb);
            w = lA0 * lA1 * lA2; a = fmaf(w, A11[2], a); bb = fmaf(w, A11[3], bb);
            feats[(size_t)l * NPTS + pt] = (uint_t)f2bf(a) | ((uint_t)f2bf(bb) << 16);
        }
        if (mB) {
            const float m0 = 1.0f - lB0, m1 = 1.0f - lB1, m2 = 1.0f - lB2;
            float a = 0.0f, bb = 0.0f, w;
            w = m0 * m1 * m2;   a = fmaf(w, B00[0], a); bb = fmaf(w, B00[1], bb);
            w = lB0 * m1 * m2;  a = fmaf(w, B00[2], a); bb = fmaf(w, B00[3], bb);
            w = m0 * lB1 * m2;  a = fmaf(w, B10[0], a); bb = fmaf(w, B10[1], bb);
            w = lB0 * lB1 * m2; a = fmaf(w, B10[2], a); bb = fmaf(w, B10[3], bb);
            w = m0 * m1 * lB2;  a = fmaf(w, B01[0], a); bb = fmaf(w, B01[1], bb);
            w = lB0 * m1 * lB2; a = fmaf(w, B01[2], a); bb = fmaf(w, B01[3], bb);
            w = m0 * lB1 * lB2; a = fmaf(w, B11[0], a); bb = fmaf(w, B11[1], bb);
            w = lB0 * lB1 * lB2; a = fmaf(w, B11[2], a); bb = fmaf(w, B11[3], bb);
            feats[(size_t)l * NPTS + ptB] = (uint_t)f2bf(a) | ((uint_t)f2bf(bb) << 16);
        }
        return;
    }

    // ---------- hash path ----------
    const float2* tp = (const float2*)tbl + ((size_t)l << 19);
    unsigned iA[8], iB[8];
    float2 cA[8], cB[8];
    if (mA) {
        const unsigned va0 = (unsigned)(int)fA0, vb0 = va0 + 1u;
        const unsigned va1 = (unsigned)(int)fA1 * HP1, vb1 = va1 + HP1;
        const unsigned va2 = (unsigned)(int)fA2 * HP2, vb2 = va2 + HP2;
        iA[0] = (va0 ^ va1 ^ va2) & TMASK;
        iA[1] = (vb0 ^ va1 ^ va2) & TMASK;
        iA[2] = (va0 ^ vb1 ^ va2) & TMASK;
        iA[3] = (vb0 ^ vb1 ^ va2) & TMASK;
        iA[4] = (va0 ^ va1 ^ vb2) & TMASK;
        iA[5] = (vb0 ^ va1 ^ vb2) & TMASK;
        iA[6] = (va0 ^ vb1 ^ vb2) & TMASK;
        iA[7] = (vb0 ^ vb1 ^ vb2) & TMASK;
    }
    if (mB) {
        const unsigned va0 = (unsigned)(int)fB0, vb0 = va0 + 1u;
        const unsigned va1 = (unsigned)(int)fB1 * HP1, vb1 = va1 + HP1;
        const unsigned va2 = (unsigned)(int)fB2 * HP2, vb2 = va2 + HP2;
        iB[0] = (va0 ^ va1 ^ va2) & TMASK;
        iB[1] = (vb0 ^ va1 ^ va2) & TMASK;
        iB[2] = (va0 ^ vb1 ^ va2) & TMASK;
        iB[3] = (vb0 ^ vb1 ^ va2) & TMASK;
        iB[4] = (va0 ^ va1 ^ vb2) & TMASK;
        iB[5] = (vb0 ^ va1 ^ vb2) & TMASK;
        iB[6] = (va0 ^ vb1 ^ vb2) & TMASK;
        iB[7] = (vb0 ^ vb1 ^ vb2) & TMASK;
    }
    if (mA) {
        #pragma unroll
        for (int k = 0; k < 8; ++k) cA[k] = tp[iA[k]];
    }
    if (mB) {
        #pragma unroll
        for (int k = 0; k < 8; ++k) cB[k] = tp[iB[k]];
    }
    if (mA) {
        const float m0 = 1.0f - lA0, m1 = 1.0f - lA1, m2 = 1.0f - lA2;
        float a = 0.0f, bb = 0.0f, w;
        w = m0 * m1 * m2;   a = fmaf(w, cA[0].x, a); bb = fmaf(w, cA[0].y, bb);
        w = lA0 * m1 * m2;  a = fmaf(w, cA[1].x, a); bb = fmaf(w, cA[1].y, bb);
        w = m0 * lA1 * m2;  a = fmaf(w, cA[2].x, a); bb = fmaf(w, cA[2].y, bb);
        w = lA0 * lA1 * m2; a = fmaf(w, cA[3].x, a); bb = fmaf(w, cA[3].y, bb);
        w = m0 * m1 * lA2;  a = fmaf(w, cA[4].x, a); bb = fmaf(w, cA[4].y, bb);
        w = lA0 * m1 * lA2; a = fmaf(w, cA[5].x, a); bb = fmaf(w, cA[5].y, bb);
        w = m0 * lA1 * lA2; a = fmaf(w, cA[6].x, a); bb = fmaf(w, cA[6].y, bb);
        w = lA0 * lA1 * lA2; a = fmaf(w, cA[7].x, a); bb = fmaf(w, cA[7].y, bb);
        feats[(size_t)l * NPTS + pt] = (uint_t)f2bf(a) | ((uint_t)f2bf(bb) << 16);
    }
    if (mB) {
        const float m0 = 1.0f - lB0, m1 = 1.0f - lB1, m2 = 1.0f - lB2;
        float a = 0.0f, bb = 0.0f, w;
        w = m0 * m1 * m2;   a = fmaf(w, cB[0].x, a); bb = fmaf(w, cB[0].y, bb);
        w = lB0 * m1 * m2;  a = fmaf(w, cB[1].x, a); bb = fmaf(w, cB[1].y, bb);
        w = m0 * lB1 * m2;  a = fmaf(w, cB[2].x, a); bb = fmaf(w, cB[2].y, bb);
        w = lB0 * lB1 * m2; a = fmaf(w, cB[3].x, a); bb = fmaf(w, cB[3].y, bb);
        w = m0 * m1 * lB2;  a = fmaf(w, cB[4].x, a); bb = fmaf(w, cB[4].y, bb);
        w = lB0 * m1 * lB2; a = fmaf(w, cB[5].x, a); bb = fmaf(w, cB[5].y, bb);
        w = m0 * lB1 * lB2; a = fmaf(w, cB[6].x, a); bb = fmaf(w, cB[6].y, bb);
        w = lB0 * lB1 * lB2; a = fmaf(w, cB[7].x, a); bb = fmaf(w, cB[7].y, bb);
        feats[(size_t)l * NPTS + ptB] = (uint_t)f2bf(a) | ((uint_t)f2bf(bb) << 16);
    }
}

// ---------------- Kernel B: MFMA MLPs (R3-verified) ----------------
extern "C" __global__ void __launch_bounds__(256) ngp_mlp(
    const float* __restrict__ xin, const float* __restrict__ din,
    const uint_t* __restrict__ featsbf, const ushort_t* __restrict__ wf,
    const float* __restrict__ db1, const float* __restrict__ db2,
    const float* __restrict__ cb1, const float* __restrict__ cb2,
    const float* __restrict__ cb3,
    float* __restrict__ out)
{
    __shared__ short act[4][4096];
    __shared__ float mk[4][64];

    const int w    = (int)threadIdx.x >> 6;
    const int lane = (int)threadIdx.x & 63;
    const int lrow = lane & 15;
    const int lq   = lane >> 4;
    const int ptb  = blockIdx.x * 256 + w * 64;
    const int p    = ptb + lane;
    char* Ab = (char*)&act[w][0];

#define LDSA(mt, kc) (*reinterpret_cast<const short8*>(Ab + ((((mt) * 16 + lrow) * 128 + (kc) * 64 + lq * 16) ^ ((lrow & 7) << 4))))
#define LOADB(off)   (*reinterpret_cast<const short8*>(wf + (off) + lane * 8))
#define STB16(row, col, val) *reinterpret_cast<ushort_t*>(Ab + ((((row) * 128 + (col) * 2)) ^ (((row) & 7) << 4))) = (val)

    const float x0 = xin[3 * p + 0];
    const float x1 = xin[3 * p + 1];
    const float x2 = xin[3 * p + 2];
    const bool msk = (fabsf(x0) < 1.5f) & (fabsf(x1) < 1.5f) & (fabsf(x2) < 1.5f);
    mk[w][lane] = msk ? 1.0f : 0.0f;

    uint_t u[16];
    #pragma unroll
    for (int l = 0; l < 16; ++l) u[l] = featsbf[(size_t)l * NPTS + p];
    #pragma unroll
    for (int c = 0; c < 4; ++c) {
        short8 v;
        #pragma unroll
        for (int q = 0; q < 4; ++q) {
            v[2 * q + 0] = (short)(u[4 * c + q] & 0xFFFFu);
            v[2 * q + 1] = (short)(u[4 * c + q] >> 16);
        }
        const int byte = (lane * 128 + 16 * c) ^ ((lane & 7) << 4);
        *reinterpret_cast<short8*>(Ab + byte) = v;
    }
    const float d0v = din[3 * p + 0];
    const float d1v = din[3 * p + 1];
    const float d2v = din[3 * p + 2];

    __syncthreads();

    // ---- Layer D1: feats[64x32] @ dW1[32x64] ----
    f32x4 acc[4][4];
    #pragma unroll
    for (int nt = 0; nt < 4; ++nt) {
        const float b = db1[nt * 16 + lrow];
        #pragma unroll
        for (int mt = 0; mt < 4; ++mt) acc[mt][nt] = (f32x4){b, b, b, b};
    }
    {
        short8 a0 = LDSA(0, 0), a1 = LDSA(1, 0), a2 = LDSA(2, 0), a3 = LDSA(3, 0);
        #pragma unroll
        for (int nt = 0; nt < 4; ++nt) {
            const short8 B = LOADB(OFF_DW1 + nt * 512);
            acc[0][nt] = MFMA(a0, B, acc[0][nt]);
            acc[1][nt] = MFMA(a1, B, acc[1][nt]);
            acc[2][nt] = MFMA(a2, B, acc[2][nt]);
            acc[3][nt] = MFMA(a3, B, acc[3][nt]);
        }
    }
    __syncthreads();
    #pragma unroll
    for (int mt = 0; mt < 4; ++mt)
        #pragma unroll
        for (int nt = 0; nt < 4; ++nt)
            #pragma unroll
            for (int r = 0; r < 4; ++r) {
                const int row = mt * 16 + lq * 4 + r;
                STB16(row, nt * 16 + lrow, f2bf(fmaxf(acc[mt][nt][r], 0.0f)));
            }
    __syncthreads();

    // ---- Layer D2: hid[64x64] @ dW2[64x16] ----
    f32x4 hD[4];
    {
        const float b = db2[lrow];
        #pragma unroll
        for (int mt = 0; mt < 4; ++mt) hD[mt] = (f32x4){b, b, b, b};
        #pragma unroll
        for (int kc = 0; kc < 2; ++kc) {
            const short8 B = LOADB(OFF_DW2 + kc * 512);
            #pragma unroll
            for (int mt = 0; mt < 4; ++mt) hD[mt] = MFMA(LDSA(mt, kc), B, hD[mt]);
        }
    }
    __syncthreads();

    if (lrow == 0) {
        #pragma unroll
        for (int mt = 0; mt < 4; ++mt)
            #pragma unroll
            for (int r = 0; r < 4; ++r) {
                const int row = mt * 16 + lq * 4 + r;
                const float mm = mk[w][row];
                out[3 * NPTS + ptb + row] = (mm != 0.0f) ? __expf(hD[mt][r]) : 0.0f;
            }
    }
    #pragma unroll
    for (int mt = 0; mt < 4; ++mt)
        #pragma unroll
        for (int r = 0; r < 4; ++r) {
            const int row = mt * 16 + lq * 4 + r;
            STB16(row, lrow, f2bf(hD[mt][r]));
        }
    {
        ushort_t t[48];
        t[0] = f2bf(d0v); t[1] = f2bf(d1v); t[2] = f2bf(d2v);
        #pragma unroll
        for (int j = 0; j < 4; ++j) {
            const float s = (float)(1 << j);
            t[3 + 6 * j + 0] = f2bf(__sinf(s * d0v));
            t[3 + 6 * j + 1] = f2bf(__sinf(s * d1v));
            t[3 + 6 * j + 2] = f2bf(__sinf(s * d2v));
            t[3 + 6 * j + 3] = f2bf(__cosf(s * d0v));
            t[3 + 6 * j + 4] = f2bf(__cosf(s * d1v));
            t[3 + 6 * j + 5] = f2bf(__cosf(s * d2v));
        }
        #pragma unroll
        for (int i = 27; i < 48; ++i) t[i] = 0;
        #pragma unroll
        for (int c = 0; c < 6; ++c) {
            short8 v;
            #pragma unroll
            for (int j = 0; j < 8; ++j) v[j] = (short)t[8 * c + j];
            const int byte = (lane * 128 + 32 + 16 * c) ^ ((lane & 7) << 4);
            *reinterpret_cast<short8*>(Ab + byte) = v;
        }
    }
    __syncthreads();

    // ---- Layer C1: ch[64x64(43)] @ cW1[64x64] ----
    #pragma unroll
    for (int nt = 0; nt < 4; ++nt) {
        const float b = cb1[nt * 16 + lrow];
        #pragma unroll
        for (int mt = 0; mt < 4; ++mt) acc[mt][nt] = (f32x4){b, b, b, b};
    }
    #pragma unroll
    for (int kc = 0; kc < 2; ++kc) {
        short8 a0 = LDSA(0, kc), a1 = LDSA(1, kc), a2 = LDSA(2, kc), a3 = LDSA(3, kc);
        #pragma unroll
        for (int nt = 0; nt < 4; ++nt) {
            const short8 B = LOADB(OFF_CW1 + (kc * 4 + nt) * 512);
            acc[0][nt] = MFMA(a0, B, acc[0][nt]);
            acc[1][nt] = MFMA(a1, B, acc[1][nt]);
            acc[2][nt] = MFMA(a2, B, acc[2][nt]);
            acc[3][nt] = MFMA(a3, B, acc[3][nt]);
        }
    }
    __syncthreads();
    #pragma unroll
    for (int mt = 0; mt < 4; ++mt)
        #pragma unroll
        for (int nt = 0; nt < 4; ++nt)
            #pragma unroll
            for (int r = 0; r < 4; ++r) {
                const int row = mt * 16 + lq * 4 + r;
                STB16(row, nt * 16 + lrow, f2bf(fmaxf(acc[mt][nt][r], 0.0f)));
            }
    __syncthreads();

    // ---- Layer C2: c1[64x64] @ cW2[64x64] ----
    #pragma unroll
    for (int nt = 0; nt < 4; ++nt) {
        const float b = cb2[nt * 16 + lrow];
        #pragma unroll
        for (int mt = 0; mt < 4; ++mt) acc[mt][nt] = (f32x4){b, b, b, b};
    }
    #pragma unroll
    for (int kc = 0; kc < 2; ++kc) {
        short8 a0 = LDSA(0, kc), a1 = LDSA(1, kc), a2 = LDSA(2, kc), a3 = LDSA(3, kc);
        #pragma unroll
        for (int nt = 0; nt < 4; ++nt) {
            const short8 B = LOADB(OFF_CW2 + (kc * 4 + nt) * 512);
            acc[0][nt] = MFMA(a0, B, acc[0][nt]);
            acc[1][nt] = MFMA(a1, B, acc[1][nt]);
            acc[2][nt] = MFMA(a2, B, acc[2][nt]);
            acc[3][nt] = MFMA(a3, B, acc[3][nt]);
        }
    }
    __syncthreads();
    #pragma unroll
    for (int mt = 0; mt < 4; ++mt)
        #pragma unroll
        for (int nt = 0; nt < 4; ++nt)
            #pragma unroll
            for (int r = 0; r < 4; ++r) {
                const int row = mt * 16 + lq * 4 + r;
                STB16(row, nt * 16 + lrow, f2bf(fmaxf(acc[mt][nt][r], 0.0f)));
            }
    __syncthreads();

    // ---- Layer C3: c2[64x64] @ cW3[64x3(pad16)] ----
    f32x4 rD[4];
    {
        const float b = (lrow < 3) ? cb3[lrow] : 0.0f;
        #pragma unroll
        for (int mt = 0; mt < 4; ++mt) rD[mt] = (f32x4){b, b, b, b};
        #pragma unroll
        for (int kc = 0; kc < 2; ++kc) {
            const short8 B = LOADB(OFF_CW3 + kc * 512);
            #pragma unroll
            for (int mt = 0; mt < 4; ++mt) rD[mt] = MFMA(LDSA(mt, kc), B, rD[mt]);
        }
    }
    if (lrow < 3) {
        #pragma unroll
        for (int mt = 0; mt < 4; ++mt)
            #pragma unroll
            for (int r = 0; r < 4; ++r) {
                const int row = mt * 16 + lq * 4 + r;
                const float mm = mk[w][row];
                out[3 * (ptb + row) + lrow] = (mm != 0.0f) ? sigmoidf_fast(rD[mt][r]) : 0.0f;
            }
    }
#undef LDSA
#undef LOADB
#undef STB16
}

extern "C" void kernel_launch(void* const* d_in, const int* in_sizes, int n_in,
                              void* d_out, int out_size, void* d_ws, size_t ws_size,
                              hipStream_t stream) {
    const float* x    = (const float*)d_in[0];
    const float* d    = (const float*)d_in[1];
    const float* tbl  = (const float*)d_in[2];
    const float* dW1  = (const float*)d_in[3];
    const float* db1  = (const float*)d_in[4];
    const float* dW2  = (const float*)d_in[5];
    const float* db2  = (const float*)d_in[6];
    const float* cW1  = (const float*)d_in[7];
    const float* cb1  = (const float*)d_in[8];
    const float* cW2  = (const float*)d_in[9];
    const float* cb2  = (const float*)d_in[10];
    const float* cW3  = (const float*)d_in[11];
    const float* cb3  = (const float*)d_in[12];

    uint_t* feats = (uint_t*)d_ws;                               // 16 MB
    f32x4* dense  = (f32x4*)((char*)d_ws + WS_DN_OFF);           // 5.31 MB
    ushort_t* wfr = (ushort_t*)((char*)d_ws + WS_WF_OFF);        // 24 KB

    ngp_prep<<<48, 256, 0, stream>>>(dW1, dW2, cW1, cW2, cW3, wfr);
    ngp_dense<<<(DTOT + 255) / 256, 256, 0, stream>>>(tbl, dense);
    ngp_encode<<<16 * 512, 256, 0, stream>>>(x, tbl, dense, feats);
    ngp_mlp<<<NPTS / 256, 256, 0, stream>>>(
        x, d, feats, wfr, db1, db2, cb1, cb2, cb3, (float*)d_out);
}